// Round 21
// baseline (122.964 us; speedup 1.0000x reference)
//
#include <hip/hip_runtime.h>
#include <hip/hip_bf16.h>

#define DEVI __device__ __forceinline__

typedef unsigned short u16;
typedef unsigned int u32;
typedef __attribute__((ext_vector_type(8))) short bf16x8;   // 8 bf16 bit-patterns (4 VGPRs)
typedef __attribute__((ext_vector_type(4))) short bf16x4;
typedef __attribute__((ext_vector_type(4))) float f32x4;

#define Bn 2
#define Tn 2048
#define Hn 16
#define Dn 64
#define Fn 1024

// f32 -> bf16 via HW conversion (RNE); adjacent pairs fuse to v_cvt_pk_bf16_f32
DEVI u16 tobf(float f) {
    __hip_bfloat16 h = __float2bfloat16(f);
    return __builtin_bit_cast(u16, h);
}
DEVI float frombf(u16 u) {
    return __builtin_bit_cast(float, ((u32)u) << 16);
}

DEVI f32x4 mfma16(bf16x8 a, bf16x8 b, f32x4 c) {
    return __builtin_amdgcn_mfma_f32_16x16x32_bf16(a, b, c, 0, 0, 0);
}

// async global->LDS, 16B per lane. LDS dest must be wave-uniform base + lane*16.
DEVI void gload_lds16(const u16* g, u16* l) {
    __builtin_amdgcn_global_load_lds(
        (const __attribute__((address_space(1))) void*)g,
        (__attribute__((address_space(3))) void*)l, 16, 0, 0);
}

// ---------------------------------------------------------------------------
// Fused prep: blocks [0,4096) do RoPE on q/k + cast to bf16;
// blocks [4096,8192) cast value + 4 weights to bf16.  [frozen; at HBM BW]
// ---------------------------------------------------------------------------
__global__ __launch_bounds__(256) void k_prep(const float* __restrict__ q,
                                              const float* __restrict__ k,
                                              const float* __restrict__ v,
                                              const float* __restrict__ cosb,
                                              const float* __restrict__ sinb,
                                              const float* __restrict__ wq,
                                              const float* __restrict__ wk,
                                              const float* __restrict__ wv,
                                              const float* __restrict__ wo,
                                              u16* __restrict__ Aq,
                                              u16* __restrict__ Ak,
                                              u16* __restrict__ Av) {
    if (blockIdx.x < 4096) {
        // --- RoPE: cos/sin indexed [t][d], pair (d, d+-32) ---
        unsigned idx = blockIdx.x * 256 + threadIdx.x;  // < 1048576
        unsigned which = idx >> 19;
        unsigned r = idx & 0x7FFFFu;
        unsigned d0 = (r & 7u) << 2;
        unsigned h = (r >> 3) & 15u;
        unsigned t = (r >> 7) & 2047u;
        unsigned b = (r >> 18) & 1u;
        const float* src = which ? k : q;
        u16* dst = which ? Ak : Aq;
        size_t base = ((size_t)(b * Tn + t)) * Fn + h * Dn;
        float4 lo = *(const float4*)(src + base + d0);
        float4 hi = *(const float4*)(src + base + d0 + 32);
        float4 cl = *(const float4*)(cosb + (size_t)t * Dn + d0);
        float4 ch = *(const float4*)(cosb + (size_t)t * Dn + d0 + 32);
        float4 sl = *(const float4*)(sinb + (size_t)t * Dn + d0);
        float4 sh = *(const float4*)(sinb + (size_t)t * Dn + d0 + 32);
        bf16x4 olo, ohi;
        olo[0] = (short)tobf(lo.x * cl.x - hi.x * sl.x);
        olo[1] = (short)tobf(lo.y * cl.y - hi.y * sl.y);
        olo[2] = (short)tobf(lo.z * cl.z - hi.z * sl.z);
        olo[3] = (short)tobf(lo.w * cl.w - hi.w * sl.w);
        ohi[0] = (short)tobf(hi.x * ch.x + lo.x * sh.x);
        ohi[1] = (short)tobf(hi.y * ch.y + lo.y * sh.y);
        ohi[2] = (short)tobf(hi.z * ch.z + lo.z * sh.z);
        ohi[3] = (short)tobf(hi.w * ch.w + lo.w * sh.w);
        *(bf16x4*)(dst + base + d0) = olo;
        *(bf16x4*)(dst + base + d0 + 32) = ohi;
    } else {
        // --- cast value(4M) + wq/wk/wv/wo(1M each) into [Av|Wq|Wk|Wv|Wo] ---
        size_t i8 = (((size_t)blockIdx.x - 4096) * 256 + threadIdx.x) * 8;  // < 8M
        const size_t M4 = (size_t)4 << 20, M1 = (size_t)1 << 20;
        const float* src;
        size_t off;
        if (i8 < M4)              { src = v;  off = i8; }
        else if (i8 < M4 + M1)    { src = wq; off = i8 - M4; }
        else if (i8 < M4 + 2*M1)  { src = wk; off = i8 - M4 - M1; }
        else if (i8 < M4 + 3*M1)  { src = wv; off = i8 - M4 - 2*M1; }
        else                      { src = wo; off = i8 - M4 - 3*M1; }
        float4 a = *(const float4*)(src + off);
        float4 c = *(const float4*)(src + off + 4);
        bf16x8 vv;
        vv[0] = (short)tobf(a.x); vv[1] = (short)tobf(a.y);
        vv[2] = (short)tobf(a.z); vv[3] = (short)tobf(a.w);
        vv[4] = (short)tobf(c.x); vv[5] = (short)tobf(c.y);
        vv[6] = (short)tobf(c.z); vv[7] = (short)tobf(c.w);
        *(bf16x8*)(Av + i8) = vv;
    }
}

// ---------------------------------------------------------------------------
// NT GEMM [frozen R16 config]: m97 2-barrier, BK=32, 8KB x2 LDS, 128x128
// tile, R11 staging coalescing + per-row XOR swizzle (pre-swizzled global
// source; 2-way banks). Direct scalar-store epilogue. T1 XCD swizzle.
// Epilogue modes: 0 = row-major C; 1 = attn K-fragment; 2 = attn V^T-frag.
// ---------------------------------------------------------------------------
DEVI void store_out(u16* p, float v) { *p = tobf(v); }
DEVI void store_out(float* p, float v) { *p = v; }

template <typename OUT>
DEVI void gemm_body(const u16* __restrict__ A, const u16* __restrict__ W,
                    const float* __restrict__ bias, OUT* __restrict__ C,
                    float scale, u16* As, u16* Bs, int mode) {
    const int tid = threadIdx.x;
    const int lane = tid & 63;
    const int wave = tid >> 6;
    const int l15 = lane & 15, l4 = lane >> 4;
    // XCD-aware tile swizzle (gridDim = (8, 32, z)); id in [0,256)
    const int id = blockIdx.x + (blockIdx.y << 3);
    const int swz = ((id & 7) << 5) + (id >> 3);         // XCD-contiguous chunks
    const int bn = (swz & 7) << 7, bm = (swz >> 3) << 7;
    const int wr = (wave >> 1) << 6, wc = (wave & 1) << 6;

    // staging: chunk c (16B), row = c>>2, colchunk = (c&3) ^ g(row),
    // g(r) = (r>>1)&3. LDS dest = slot c (byte c*16): wave-uniform + lane*16.
    const int c0 = tid, c1 = tid + 256;
    const int r0 = c0 >> 2, r1 = c1 >> 2;
    const int cc0 = (((c0 & 3) ^ ((r0 >> 1) & 3)) << 3);
    const int cc1 = (((c1 & 3) ^ ((r1 >> 1) & 3)) << 3);
    const u16* A0p = A + (size_t)(bm + r0) * 1024 + cc0;
    const u16* A1p = A + (size_t)(bm + r1) * 1024 + cc1;
    const u16* B0p = W + (size_t)(bn + r0) * 1024 + cc0;
    const u16* B1p = W + (size_t)(bn + r1) * 1024 + cc1;
    u16* Ad0 = As + (c0 << 3);
    u16* Ad1 = As + (c1 << 3);
    u16* Bd0 = Bs + (c0 << 3);
    u16* Bd1 = Bs + (c1 << 3);

    // fragment-read swizzled colchunk offset (u16): (l4 ^ g) * 8
    const int gsw = (l15 >> 1) & 3;
    const int fco = ((l4 ^ gsw) << 3);

    f32x4 acc[4][4] = {};

    for (int k0 = 0; k0 < 1024; k0 += 32) {
        gload_lds16(A0p + k0, Ad0);
        gload_lds16(A1p + k0, Ad1);
        gload_lds16(B0p + k0, Bd0);
        gload_lds16(B1p + k0, Bd1);
        __syncthreads();  // drains vmcnt -> LDS tile ready (m97 structure)
        bf16x8 af[4], bfr[4];
        #pragma unroll
        for (int m = 0; m < 4; m++)
            af[m] = *(const bf16x8*)(As + (wr + m * 16 + l15) * 32 + fco);
        #pragma unroll
        for (int n = 0; n < 4; n++)
            bfr[n] = *(const bf16x8*)(Bs + (wc + n * 16 + l15) * 32 + fco);
        #pragma unroll
        for (int m = 0; m < 4; m++)
            #pragma unroll
            for (int n = 0; n < 4; n++)
                acc[m][n] = mfma16(af[m], bfr[n], acc[m][n]);
        __syncthreads();  // all waves done reading before overwrite
    }

    // C/D layout: col = lane&15, row = (lane>>4)*4 + j  (m89-verified)
    #pragma unroll
    for (int m = 0; m < 4; m++)
        #pragma unroll
        for (int n = 0; n < 4; n++) {
            const int gcol = bn + wc + n * 16 + l15;
            const float bb = bias[gcol];
            #pragma unroll
            for (int j = 0; j < 4; j++) {
                const int grow = bm + wr + m * 16 + (l4 << 2) + j;
                const float val = (acc[m][n][j] + bb) * scale;
                if (mode == 0) {
                    store_out(C + (size_t)grow * 1024 + gcol, val);
                } else {
                    // map (grow,gcol) -> attn fragment-linear slot
                    const int b = grow >> 11, t = grow & 2047;
                    const int h = gcol >> 6, d = gcol & 63;
                    const int bh = b * 16 + h, tt2 = t >> 6, r = t & 63;
                    const size_t tbase = ((size_t)(bh * 32 + tt2)) << 12;
                    size_t off;
                    if (mode == 1) {   // Kr: chunk = n*2+kk (kv-row permuted)
                        const int nn = ((r >> 5) << 1) | ((r >> 2) & 1);
                        const int kk = d >> 5, ll4 = (d >> 3) & 3, e = d & 7;
                        const int ll15 = (((r >> 3) & 3) << 2) | (r & 3);
                        off = tbase + ((size_t)(nn * 2 + kk) << 9) +
                              ((ll4 * 16 + ll15) << 3) + e;
                    } else {           // Vr: chunk = kk*4+nd (V^T frag)
                        const int kk = r >> 5, ll4 = (r >> 3) & 3, e = r & 7;
                        const int nd = d >> 4, ll15 = d & 15;
                        off = tbase + ((size_t)(kk * 4 + nd) << 9) +
                              ((ll4 * 16 + ll15) << 3) + e;
                    }
                    ((u16*)C)[off] = tobf(val);
                }
            }
        }
}

__global__ __launch_bounds__(256) void k_gemm_qkv(
    const u16* A0, const u16* W0, const float* b0, u16* C0,
    const u16* A1, const u16* W1, const float* b1, u16* C1,
    const u16* A2, const u16* W2, const float* b2, u16* C2) {
    __shared__ __align__(16) u16 As[128 * 32];   // 8 KB single buffer
    __shared__ __align__(16) u16 Bs[128 * 32];   // 8 KB
    const int z = blockIdx.z;
    const u16* A = z == 0 ? A0 : (z == 1 ? A1 : A2);
    const u16* W = z == 0 ? W0 : (z == 1 ? W1 : W2);
    const float* bias = z == 0 ? b0 : (z == 1 ? b1 : b2);
    u16* C = z == 0 ? C0 : (z == 1 ? C1 : C2);
    // Q gets 1/sqrt(64) * log2(e) folded in (softmax uses exp2)
    const float scale = z == 0 ? 0.125f * 1.4426950408889634f : 1.0f;
    gemm_body<u16>(A, W, bias, C, scale, As, Bs, z);
}

__global__ __launch_bounds__(256) void k_gemm_f32(const u16* __restrict__ A,
                                                  const u16* __restrict__ W,
                                                  const float* __restrict__ bias,
                                                  float* __restrict__ C) {
    __shared__ __align__(16) u16 As[128 * 32];
    __shared__ __align__(16) u16 Bs[128 * 32];
    gemm_body<float>(A, W, bias, C, 1.0f, As, Bs, 0);
}

// ---------------------------------------------------------------------------
// Flash attention, non-causal, swapped-operand, exp2 domain, FIXED-MAX.
// kv-split=1 (no combine), 32 kv-tiles/block, LDS-shared K/V double-buffer.
// R21: 2-WAVE BLOCKS (128 thr, 64 q-rows/block; grid 32x32 = 1024 blocks =
// 4 blocks/CU). Per-wave work unchanged (32 q-rows); barrier groups 4->2
// waves (half the sync skew) and 4 independent blocks/CU (vs 2) restore the
// m114 block-level overlap that 512-block R19 starved. Waves/CU unchanged.
// LDS 32KB/block x4 = 128KB <= 160. XCD locality: id%8 = bh%8.
// Arithmetic identical -> absmax bit-exact.
// ---------------------------------------------------------------------------
__global__ __launch_bounds__(128) void k_attn(const u16* __restrict__ Qp,
                                              const u16* __restrict__ Kr,
                                              const u16* __restrict__ Vr,
                                              u16* __restrict__ Oa) {
    __shared__ __align__(16) u16 Ks[2][4096];   // 8 KB per buffer (1 tile)
    __shared__ __align__(16) u16 Vs[2][4096];
    const int tid = threadIdx.x, wave = tid >> 6, lane = tid & 63;
    const int l15 = lane & 15, l4 = lane >> 4;
    const int bh = blockIdx.x, b = bh >> 4, h = bh & 15;
    const int q0 = blockIdx.y * 64 + wave * 32;

    // Q as B-frag (pre-scaled by log2e/8): col = q = l15, k at l4*8 (+32*kk)
    bf16x8 aq[2][2];
    #pragma unroll
    for (int mq = 0; mq < 2; mq++)
        #pragma unroll
        for (int kk = 0; kk < 2; kk++)
            aq[mq][kk] = *(const bf16x8*)(Qp +
                ((size_t)(b * Tn + q0 + mq * 16 + l15)) * Fn + h * Dn + kk * 32 + (l4 << 3));

    f32x4 o[2][4] = {};                 // O^T: lane q=l15, d = nd*16+l4*4+r
    f32x4 osum[2] = {};                 // running row-sums via mfma C-in chain
    const f32x4 zero4 = {0.f, 0.f, 0.f, 0.f};

    bf16x8 ones;
    #pragma unroll
    for (int j = 0; j < 8; j++) ones[j] = (short)0x3F80;   // bf16 1.0

    const u16* Kbr = Kr + ((size_t)bh << 17);      // 32 tiles * 4096 u16
    const u16* Vbr = Vr + ((size_t)bh << 17);
    const int lo8 = lane * 8;

    // stage tile tg's 8+8 1KB chunks into buffer bf; wave w (of 2) takes
    // chunks w, w+2, w+4, w+6 of each matrix.
    // LDS dest = wave-uniform base + lane*16B (required by global_load_lds).
    #define STAGE(bf, tg)                                                     \
        _Pragma("unroll")                                                     \
        for (int i = 0; i < 4; i++) {                                         \
            const int c = wave + i * 2;                                       \
            gload_lds16(Kbr + (((tg) * 8 + c) << 9) + lo8,                    \
                        &Ks[bf][(c << 9) + lo8]);                             \
            gload_lds16(Vbr + (((tg) * 8 + c) << 9) + lo8,                    \
                        &Vs[bf][(c << 9) + lo8]);                             \
        }

    STAGE(0, 0);
    __syncthreads();                    // prologue: buffer 0 ready
    int cur = 0;

    #pragma unroll 1
    for (int tt = 0; tt < 32; tt++) {
        if (tt < 31) STAGE(cur ^ 1, tt + 1);          // async, lands during compute

        // read K/V fragments from shared LDS (contiguous b128, conflict-free)
        bf16x8 ka[4][2], va[2][4];
        #pragma unroll
        for (int n = 0; n < 4; n++)
            #pragma unroll
            for (int kk = 0; kk < 2; kk++)
                ka[n][kk] = *(const bf16x8*)(&Ks[cur][((n * 2 + kk) << 9) + lo8]);
        #pragma unroll
        for (int kk = 0; kk < 2; kk++)
            #pragma unroll
            for (int nd = 0; nd < 4; nd++)
                va[kk][nd] = *(const bf16x8*)(&Vs[cur][((kk * 4 + nd) << 9) + lo8]);

        // S^T: s[mq][n][r] = S2[q=l15][kv = tt*64 + l4*8 + (n&1)*4 + r + (n>>1)*32]
        f32x4 s[2][4];
        __builtin_amdgcn_s_setprio(1);
        #pragma unroll
        for (int n = 0; n < 4; n++) {
            s[0][n] = mfma16(ka[n][0], aq[0][0], zero4);
            s[1][n] = mfma16(ka[n][0], aq[1][0], zero4);
            s[0][n] = mfma16(ka[n][1], aq[0][1], s[0][n]);
            s[1][n] = mfma16(ka[n][1], aq[1][1], s[1][n]);
        }
        __builtin_amdgcn_s_setprio(0);

        // P = exp2(s) (no max), pack to bf16 PV B-fragments; all independent
        bf16x8 pb[2][2];
        #pragma unroll
        for (int mq = 0; mq < 2; mq++)
            #pragma unroll
            for (int kk = 0; kk < 2; kk++) {
                float p0 = __builtin_amdgcn_exp2f(s[mq][2 * kk][0]);
                float p1 = __builtin_amdgcn_exp2f(s[mq][2 * kk][1]);
                float p2 = __builtin_amdgcn_exp2f(s[mq][2 * kk][2]);
                float p3 = __builtin_amdgcn_exp2f(s[mq][2 * kk][3]);
                float p4 = __builtin_amdgcn_exp2f(s[mq][2 * kk + 1][0]);
                float p5 = __builtin_amdgcn_exp2f(s[mq][2 * kk + 1][1]);
                float p6 = __builtin_amdgcn_exp2f(s[mq][2 * kk + 1][2]);
                float p7 = __builtin_amdgcn_exp2f(s[mq][2 * kk + 1][3]);
                bf16x8 pv;
                pv[0] = (short)tobf(p0); pv[1] = (short)tobf(p1);
                pv[2] = (short)tobf(p2); pv[3] = (short)tobf(p3);
                pv[4] = (short)tobf(p4); pv[5] = (short)tobf(p5);
                pv[6] = (short)tobf(p6); pv[7] = (short)tobf(p7);
                pb[mq][kk] = pv;
            }

        // O^T += Vt P^T; row-sum accumulates in osum via mfma C-in chain
        __builtin_amdgcn_s_setprio(1);
        osum[0] = mfma16(ones, pb[0][0], osum[0]);
        osum[1] = mfma16(ones, pb[1][0], osum[1]);
        osum[0] = mfma16(ones, pb[0][1], osum[0]);
        osum[1] = mfma16(ones, pb[1][1], osum[1]);
        #pragma unroll
        for (int kk = 0; kk < 2; kk++)
            #pragma unroll
            for (int nd = 0; nd < 4; nd++) {
                o[0][nd] = mfma16(va[kk][nd], pb[0][kk], o[0][nd]);
                o[1][nd] = mfma16(va[kk][nd], pb[1][kk], o[1][nd]);
            }
        __builtin_amdgcn_s_setprio(0);

        // barrier: staging of t+1 done (had whole compute to land) AND all
        // waves finished reading buf[cur] before it is overwritten at t+2.
        __syncthreads();
        cur ^= 1;
    }
    #undef STAGE

    // epilogue: final normalized O = o / lsum (full row covered, no combine)
    #pragma unroll
    for (int mq = 0; mq < 2; mq++) {
        const int q = q0 + mq * 16 + l15;
        float inv = 1.f / osum[mq][0];
        #pragma unroll
        for (int nd = 0; nd < 4; nd++) {
            bf16x4 ov;
            ov[0] = (short)tobf(o[mq][nd][0] * inv);
            ov[1] = (short)tobf(o[mq][nd][1] * inv);
            ov[2] = (short)tobf(o[mq][nd][2] * inv);
            ov[3] = (short)tobf(o[mq][nd][3] * inv);
            *(bf16x4*)(Oa + ((size_t)(b * Tn + q)) * Fn +
                       h * Dn + nd * 16 + (l4 << 2)) = ov;
        }
    }
}

// ---------------------------------------------------------------------------
extern "C" void kernel_launch(void* const* d_in, const int* in_sizes, int n_in,
                              void* d_out, int out_size, void* d_ws, size_t ws_size,
                              hipStream_t stream) {
    const float* q    = (const float*)d_in[0];
    const float* k    = (const float*)d_in[1];
    const float* v    = (const float*)d_in[2];
    const float* cosb = (const float*)d_in[3];
    const float* sinb = (const float*)d_in[4];
    const float* wq   = (const float*)d_in[5];
    const float* wk   = (const float*)d_in[6];
    const float* wv   = (const float*)d_in[7];
    const float* wo   = (const float*)d_in[8];
    const float* bq   = (const float*)d_in[9];
    const float* bk   = (const float*)d_in[10];
    const float* bv   = (const float*)d_in[11];
    const float* bo   = (const float*)d_in[12];

    char* ws = (char*)d_ws;
    const size_t MB = (size_t)1 << 20;
    // Lifetime plan (ws 56 MB):
    //  prep/gemm phase: Aq[0..8) Ak[8..16) Av[16..24) W[24..32) -> Qp/Kr/Vr[32..56)
    //  attn phase: writes final Oa = ws[0..8) (Aq dead after gemm_qkv);
    //              Qp/Kr/Vr live; Wo ws[30..32)
    //  gemm_f32: A=Oa, W=Wo -> C=d_out
    u16* Aq  = (u16*)(ws);
    u16* Ak  = (u16*)(ws + 8 * MB);
    u16* Av  = (u16*)(ws + 16 * MB);
    u16* Wq  = (u16*)(ws + 24 * MB);
    u16* Wk  = (u16*)(ws + 26 * MB);
    u16* Wv  = (u16*)(ws + 28 * MB);
    u16* Wo  = (u16*)(ws + 30 * MB);
    u16* Qp  = (u16*)(ws + 32 * MB);
    u16* Kr  = (u16*)(ws + 40 * MB);
    u16* Vr  = (u16*)(ws + 48 * MB);
    u16* Oa  = Aq;

    k_prep<<<8192, 256, 0, stream>>>(q, k, v, cosb, sinb, wq, wk, wv, wo,
                                     Aq, Ak, Av);
    k_gemm_qkv<<<dim3(8, 32, 3), 256, 0, stream>>>(Aq, Wq, bq, Qp,
                                                   Ak, Wk, bk, Kr,
                                                   Av, Wv, bv, Vr);
    k_attn<<<dim3(32, 32), 128, 0, stream>>>(Qp, Kr, Vr, Oa);
    k_gemm_f32<<<dim3(8, 32), 256, 0, stream>>>(Oa, Wo, bo, (float*)d_out);
}

// Round 22
// 118.548 us; speedup vs baseline: 1.0372x; 1.0372x over previous
//
#include <hip/hip_runtime.h>
#include <hip/hip_bf16.h>

#define DEVI __device__ __forceinline__

typedef unsigned short u16;
typedef unsigned int u32;
typedef __attribute__((ext_vector_type(8))) short bf16x8;   // 8 bf16 bit-patterns (4 VGPRs)
typedef __attribute__((ext_vector_type(4))) short bf16x4;
typedef __attribute__((ext_vector_type(4))) float f32x4;

#define Bn 2
#define Tn 2048
#define Hn 16
#define Dn 64
#define Fn 1024

// f32 -> bf16 via HW conversion (RNE); adjacent pairs fuse to v_cvt_pk_bf16_f32
DEVI u16 tobf(float f) {
    __hip_bfloat16 h = __float2bfloat16(f);
    return __builtin_bit_cast(u16, h);
}
DEVI float frombf(u16 u) {
    return __builtin_bit_cast(float, ((u32)u) << 16);
}

DEVI f32x4 mfma16(bf16x8 a, bf16x8 b, f32x4 c) {
    return __builtin_amdgcn_mfma_f32_16x16x32_bf16(a, b, c, 0, 0, 0);
}

// async global->LDS, 16B per lane. LDS dest must be wave-uniform base + lane*16.
DEVI void gload_lds16(const u16* g, u16* l) {
    __builtin_amdgcn_global_load_lds(
        (const __attribute__((address_space(1))) void*)g,
        (__attribute__((address_space(3))) void*)l, 16, 0, 0);
}

// ---------------------------------------------------------------------------
// Fused prep: blocks [0,4096) do RoPE on q/k + cast to bf16;
// blocks [4096,8192) cast value + 4 weights to bf16.  [frozen; at HBM BW]
// ---------------------------------------------------------------------------
__global__ __launch_bounds__(256) void k_prep(const float* __restrict__ q,
                                              const float* __restrict__ k,
                                              const float* __restrict__ v,
                                              const float* __restrict__ cosb,
                                              const float* __restrict__ sinb,
                                              const float* __restrict__ wq,
                                              const float* __restrict__ wk,
                                              const float* __restrict__ wv,
                                              const float* __restrict__ wo,
                                              u16* __restrict__ Aq,
                                              u16* __restrict__ Ak,
                                              u16* __restrict__ Av) {
    if (blockIdx.x < 4096) {
        // --- RoPE: cos/sin indexed [t][d], pair (d, d+-32) ---
        unsigned idx = blockIdx.x * 256 + threadIdx.x;  // < 1048576
        unsigned which = idx >> 19;
        unsigned r = idx & 0x7FFFFu;
        unsigned d0 = (r & 7u) << 2;
        unsigned h = (r >> 3) & 15u;
        unsigned t = (r >> 7) & 2047u;
        unsigned b = (r >> 18) & 1u;
        const float* src = which ? k : q;
        u16* dst = which ? Ak : Aq;
        size_t base = ((size_t)(b * Tn + t)) * Fn + h * Dn;
        float4 lo = *(const float4*)(src + base + d0);
        float4 hi = *(const float4*)(src + base + d0 + 32);
        float4 cl = *(const float4*)(cosb + (size_t)t * Dn + d0);
        float4 ch = *(const float4*)(cosb + (size_t)t * Dn + d0 + 32);
        float4 sl = *(const float4*)(sinb + (size_t)t * Dn + d0);
        float4 sh = *(const float4*)(sinb + (size_t)t * Dn + d0 + 32);
        bf16x4 olo, ohi;
        olo[0] = (short)tobf(lo.x * cl.x - hi.x * sl.x);
        olo[1] = (short)tobf(lo.y * cl.y - hi.y * sl.y);
        olo[2] = (short)tobf(lo.z * cl.z - hi.z * sl.z);
        olo[3] = (short)tobf(lo.w * cl.w - hi.w * sl.w);
        ohi[0] = (short)tobf(hi.x * ch.x + lo.x * sh.x);
        ohi[1] = (short)tobf(hi.y * ch.y + lo.y * sh.y);
        ohi[2] = (short)tobf(hi.z * ch.z + lo.z * sh.z);
        ohi[3] = (short)tobf(hi.w * ch.w + lo.w * sh.w);
        *(bf16x4*)(dst + base + d0) = olo;
        *(bf16x4*)(dst + base + d0 + 32) = ohi;
    } else {
        // --- cast value(4M) + wq/wk/wv/wo(1M each) into [Av|Wq|Wk|Wv|Wo] ---
        size_t i8 = (((size_t)blockIdx.x - 4096) * 256 + threadIdx.x) * 8;  // < 8M
        const size_t M4 = (size_t)4 << 20, M1 = (size_t)1 << 20;
        const float* src;
        size_t off;
        if (i8 < M4)              { src = v;  off = i8; }
        else if (i8 < M4 + M1)    { src = wq; off = i8 - M4; }
        else if (i8 < M4 + 2*M1)  { src = wk; off = i8 - M4 - M1; }
        else if (i8 < M4 + 3*M1)  { src = wv; off = i8 - M4 - 2*M1; }
        else                      { src = wo; off = i8 - M4 - 3*M1; }
        float4 a = *(const float4*)(src + off);
        float4 c = *(const float4*)(src + off + 4);
        bf16x8 vv;
        vv[0] = (short)tobf(a.x); vv[1] = (short)tobf(a.y);
        vv[2] = (short)tobf(a.z); vv[3] = (short)tobf(a.w);
        vv[4] = (short)tobf(c.x); vv[5] = (short)tobf(c.y);
        vv[6] = (short)tobf(c.z); vv[7] = (short)tobf(c.w);
        *(bf16x8*)(Av + i8) = vv;
    }
}

// ---------------------------------------------------------------------------
// NT GEMM [frozen R16 config]: m97 2-barrier, BK=32, 8KB x2 LDS, 128x128
// tile, R11 staging coalescing + per-row XOR swizzle (pre-swizzled global
// source; 2-way banks). Direct scalar-store epilogue. T1 XCD swizzle.
// Epilogue modes: 0 = row-major C; 1 = attn K-fragment; 2 = attn V^T-frag.
// ---------------------------------------------------------------------------
DEVI void store_out(u16* p, float v) { *p = tobf(v); }
DEVI void store_out(float* p, float v) { *p = v; }

template <typename OUT>
DEVI void gemm_body(const u16* __restrict__ A, const u16* __restrict__ W,
                    const float* __restrict__ bias, OUT* __restrict__ C,
                    float scale, u16* As, u16* Bs, int mode) {
    const int tid = threadIdx.x;
    const int lane = tid & 63;
    const int wave = tid >> 6;
    const int l15 = lane & 15, l4 = lane >> 4;
    // XCD-aware tile swizzle (gridDim = (8, 32, z)); id in [0,256)
    const int id = blockIdx.x + (blockIdx.y << 3);
    const int swz = ((id & 7) << 5) + (id >> 3);         // XCD-contiguous chunks
    const int bn = (swz & 7) << 7, bm = (swz >> 3) << 7;
    const int wr = (wave >> 1) << 6, wc = (wave & 1) << 6;

    // staging: chunk c (16B), row = c>>2, colchunk = (c&3) ^ g(row),
    // g(r) = (r>>1)&3. LDS dest = slot c (byte c*16): wave-uniform + lane*16.
    const int c0 = tid, c1 = tid + 256;
    const int r0 = c0 >> 2, r1 = c1 >> 2;
    const int cc0 = (((c0 & 3) ^ ((r0 >> 1) & 3)) << 3);
    const int cc1 = (((c1 & 3) ^ ((r1 >> 1) & 3)) << 3);
    const u16* A0p = A + (size_t)(bm + r0) * 1024 + cc0;
    const u16* A1p = A + (size_t)(bm + r1) * 1024 + cc1;
    const u16* B0p = W + (size_t)(bn + r0) * 1024 + cc0;
    const u16* B1p = W + (size_t)(bn + r1) * 1024 + cc1;
    u16* Ad0 = As + (c0 << 3);
    u16* Ad1 = As + (c1 << 3);
    u16* Bd0 = Bs + (c0 << 3);
    u16* Bd1 = Bs + (c1 << 3);

    // fragment-read swizzled colchunk offset (u16): (l4 ^ g) * 8
    const int gsw = (l15 >> 1) & 3;
    const int fco = ((l4 ^ gsw) << 3);

    f32x4 acc[4][4] = {};

    for (int k0 = 0; k0 < 1024; k0 += 32) {
        gload_lds16(A0p + k0, Ad0);
        gload_lds16(A1p + k0, Ad1);
        gload_lds16(B0p + k0, Bd0);
        gload_lds16(B1p + k0, Bd1);
        __syncthreads();  // drains vmcnt -> LDS tile ready (m97 structure)
        bf16x8 af[4], bfr[4];
        #pragma unroll
        for (int m = 0; m < 4; m++)
            af[m] = *(const bf16x8*)(As + (wr + m * 16 + l15) * 32 + fco);
        #pragma unroll
        for (int n = 0; n < 4; n++)
            bfr[n] = *(const bf16x8*)(Bs + (wc + n * 16 + l15) * 32 + fco);
        #pragma unroll
        for (int m = 0; m < 4; m++)
            #pragma unroll
            for (int n = 0; n < 4; n++)
                acc[m][n] = mfma16(af[m], bfr[n], acc[m][n]);
        __syncthreads();  // all waves done reading before overwrite
    }

    // C/D layout: col = lane&15, row = (lane>>4)*4 + j  (m89-verified)
    #pragma unroll
    for (int m = 0; m < 4; m++)
        #pragma unroll
        for (int n = 0; n < 4; n++) {
            const int gcol = bn + wc + n * 16 + l15;
            const float bb = bias[gcol];
            #pragma unroll
            for (int j = 0; j < 4; j++) {
                const int grow = bm + wr + m * 16 + (l4 << 2) + j;
                const float val = (acc[m][n][j] + bb) * scale;
                if (mode == 0) {
                    store_out(C + (size_t)grow * 1024 + gcol, val);
                } else {
                    // map (grow,gcol) -> attn fragment-linear slot
                    const int b = grow >> 11, t = grow & 2047;
                    const int h = gcol >> 6, d = gcol & 63;
                    const int bh = b * 16 + h, tt2 = t >> 6, r = t & 63;
                    const size_t tbase = ((size_t)(bh * 32 + tt2)) << 12;
                    size_t off;
                    if (mode == 1) {   // Kr: chunk = n*2+kk (kv-row permuted)
                        const int nn = ((r >> 5) << 1) | ((r >> 2) & 1);
                        const int kk = d >> 5, ll4 = (d >> 3) & 3, e = d & 7;
                        const int ll15 = (((r >> 3) & 3) << 2) | (r & 3);
                        off = tbase + ((size_t)(nn * 2 + kk) << 9) +
                              ((ll4 * 16 + ll15) << 3) + e;
                    } else {           // Vr: chunk = kk*4+nd (V^T frag)
                        const int kk = r >> 5, ll4 = (r >> 3) & 3, e = r & 7;
                        const int nd = d >> 4, ll15 = d & 15;
                        off = tbase + ((size_t)(kk * 4 + nd) << 9) +
                              ((ll4 * 16 + ll15) << 3) + e;
                    }
                    ((u16*)C)[off] = tobf(val);
                }
            }
        }
}

__global__ __launch_bounds__(256) void k_gemm_qkv(
    const u16* A0, const u16* W0, const float* b0, u16* C0,
    const u16* A1, const u16* W1, const float* b1, u16* C1,
    const u16* A2, const u16* W2, const float* b2, u16* C2) {
    __shared__ __align__(16) u16 As[128 * 32];   // 8 KB single buffer
    __shared__ __align__(16) u16 Bs[128 * 32];   // 8 KB
    const int z = blockIdx.z;
    const u16* A = z == 0 ? A0 : (z == 1 ? A1 : A2);
    const u16* W = z == 0 ? W0 : (z == 1 ? W1 : W2);
    const float* bias = z == 0 ? b0 : (z == 1 ? b1 : b2);
    u16* C = z == 0 ? C0 : (z == 1 ? C1 : C2);
    // Q gets 1/sqrt(64) * log2(e) folded in (softmax uses exp2)
    const float scale = z == 0 ? 0.125f * 1.4426950408889634f : 1.0f;
    gemm_body<u16>(A, W, bias, C, scale, As, Bs, z);
}

__global__ __launch_bounds__(256) void k_gemm_f32(const u16* __restrict__ A,
                                                  const u16* __restrict__ W,
                                                  const float* __restrict__ bias,
                                                  float* __restrict__ C) {
    __shared__ __align__(16) u16 As[128 * 32];
    __shared__ __align__(16) u16 Bs[128 * 32];
    gemm_body<float>(A, W, bias, C, 1.0f, As, Bs, 0);
}

// ---------------------------------------------------------------------------
// Flash attention, non-causal, swapped-operand, exp2 domain, FIXED-MAX.
// kv-split=1 (512 blocks = 2 blocks/CU; 32 kv-tiles/block), no combine.
// [R22 = exact R19, the measured optimum: waves/block {2,4}, tiles/buffer
// {1,2}, kv-split {1,2,4} all swept; R19's point won. Frozen final.]
// Grid (x=32 bh, y=16 qtile), 4 waves, wave owns 32 q-rows.
// ---------------------------------------------------------------------------
__global__ __launch_bounds__(256) void k_attn(const u16* __restrict__ Qp,
                                              const u16* __restrict__ Kr,
                                              const u16* __restrict__ Vr,
                                              u16* __restrict__ Oa) {
    __shared__ __align__(16) u16 Ks[2][4096];   // 8 KB per buffer
    __shared__ __align__(16) u16 Vs[2][4096];
    const int tid = threadIdx.x, wave = tid >> 6, lane = tid & 63;
    const int l15 = lane & 15, l4 = lane >> 4;
    const int bh = blockIdx.x, b = bh >> 4, h = bh & 15;
    const int q0 = blockIdx.y * 128 + wave * 32;

    // Q as B-frag (pre-scaled by log2e/8): col = q = l15, k at l4*8 (+32*kk)
    bf16x8 aq[2][2];
    #pragma unroll
    for (int mq = 0; mq < 2; mq++)
        #pragma unroll
        for (int kk = 0; kk < 2; kk++)
            aq[mq][kk] = *(const bf16x8*)(Qp +
                ((size_t)(b * Tn + q0 + mq * 16 + l15)) * Fn + h * Dn + kk * 32 + (l4 << 3));

    f32x4 o[2][4] = {};                 // O^T: lane q=l15, d = nd*16+l4*4+r
    f32x4 osum[2] = {};                 // running row-sums via mfma C-in chain
    const f32x4 zero4 = {0.f, 0.f, 0.f, 0.f};

    bf16x8 ones;
    #pragma unroll
    for (int j = 0; j < 8; j++) ones[j] = (short)0x3F80;   // bf16 1.0

    const u16* Kbr = Kr + ((size_t)bh << 17);      // 32 tiles * 4096 u16
    const u16* Vbr = Vr + ((size_t)bh << 17);
    const int lo8 = lane * 8;

    // stage tile tg's 8+8 1KB chunks into buffer bf; wave w takes chunks w, w+4
    // LDS dest = wave-uniform base + lane*16B (required by global_load_lds).
    #define STAGE(bf, tg)                                                     \
        _Pragma("unroll")                                                     \
        for (int i = 0; i < 2; i++) {                                         \
            const int c = wave + i * 4;                                       \
            gload_lds16(Kbr + (((tg) * 8 + c) << 9) + lo8,                    \
                        &Ks[bf][(c << 9) + lo8]);                             \
            gload_lds16(Vbr + (((tg) * 8 + c) << 9) + lo8,                    \
                        &Vs[bf][(c << 9) + lo8]);                             \
        }

    STAGE(0, 0);
    __syncthreads();                    // prologue: buffer 0 ready
    int cur = 0;

    #pragma unroll 1
    for (int tt = 0; tt < 32; tt++) {
        if (tt < 31) STAGE(cur ^ 1, tt + 1);          // async, lands during compute

        // read K/V fragments from shared LDS (contiguous b128, conflict-free)
        bf16x8 ka[4][2], va[2][4];
        #pragma unroll
        for (int n = 0; n < 4; n++)
            #pragma unroll
            for (int kk = 0; kk < 2; kk++)
                ka[n][kk] = *(const bf16x8*)(&Ks[cur][((n * 2 + kk) << 9) + lo8]);
        #pragma unroll
        for (int kk = 0; kk < 2; kk++)
            #pragma unroll
            for (int nd = 0; nd < 4; nd++)
                va[kk][nd] = *(const bf16x8*)(&Vs[cur][((kk * 4 + nd) << 9) + lo8]);

        // S^T: s[mq][n][r] = S2[q=l15][kv = tt*64 + l4*8 + (n&1)*4 + r + (n>>1)*32]
        f32x4 s[2][4];
        __builtin_amdgcn_s_setprio(1);
        #pragma unroll
        for (int n = 0; n < 4; n++) {
            s[0][n] = mfma16(ka[n][0], aq[0][0], zero4);
            s[1][n] = mfma16(ka[n][0], aq[1][0], zero4);
            s[0][n] = mfma16(ka[n][1], aq[0][1], s[0][n]);
            s[1][n] = mfma16(ka[n][1], aq[1][1], s[1][n]);
        }
        __builtin_amdgcn_s_setprio(0);

        // P = exp2(s) (no max), pack to bf16 PV B-fragments; all independent
        bf16x8 pb[2][2];
        #pragma unroll
        for (int mq = 0; mq < 2; mq++)
            #pragma unroll
            for (int kk = 0; kk < 2; kk++) {
                float p0 = __builtin_amdgcn_exp2f(s[mq][2 * kk][0]);
                float p1 = __builtin_amdgcn_exp2f(s[mq][2 * kk][1]);
                float p2 = __builtin_amdgcn_exp2f(s[mq][2 * kk][2]);
                float p3 = __builtin_amdgcn_exp2f(s[mq][2 * kk][3]);
                float p4 = __builtin_amdgcn_exp2f(s[mq][2 * kk + 1][0]);
                float p5 = __builtin_amdgcn_exp2f(s[mq][2 * kk + 1][1]);
                float p6 = __builtin_amdgcn_exp2f(s[mq][2 * kk + 1][2]);
                float p7 = __builtin_amdgcn_exp2f(s[mq][2 * kk + 1][3]);
                bf16x8 pv;
                pv[0] = (short)tobf(p0); pv[1] = (short)tobf(p1);
                pv[2] = (short)tobf(p2); pv[3] = (short)tobf(p3);
                pv[4] = (short)tobf(p4); pv[5] = (short)tobf(p5);
                pv[6] = (short)tobf(p6); pv[7] = (short)tobf(p7);
                pb[mq][kk] = pv;
            }

        // O^T += Vt P^T; row-sum accumulates in osum via mfma C-in chain
        __builtin_amdgcn_s_setprio(1);
        osum[0] = mfma16(ones, pb[0][0], osum[0]);
        osum[1] = mfma16(ones, pb[1][0], osum[1]);
        osum[0] = mfma16(ones, pb[0][1], osum[0]);
        osum[1] = mfma16(ones, pb[1][1], osum[1]);
        #pragma unroll
        for (int kk = 0; kk < 2; kk++)
            #pragma unroll
            for (int nd = 0; nd < 4; nd++) {
                o[0][nd] = mfma16(va[kk][nd], pb[0][kk], o[0][nd]);
                o[1][nd] = mfma16(va[kk][nd], pb[1][kk], o[1][nd]);
            }
        __builtin_amdgcn_s_setprio(0);

        // barrier: staging of t+1 done (had whole compute to land) AND all
        // waves finished reading buf[cur] before it is overwritten at t+2.
        __syncthreads();
        cur ^= 1;
    }
    #undef STAGE

    // epilogue: final normalized O = o / lsum (full row covered, no combine)
    #pragma unroll
    for (int mq = 0; mq < 2; mq++) {
        const int q = q0 + mq * 16 + l15;
        float inv = 1.f / osum[mq][0];
        #pragma unroll
        for (int nd = 0; nd < 4; nd++) {
            bf16x4 ov;
            ov[0] = (short)tobf(o[mq][nd][0] * inv);
            ov[1] = (short)tobf(o[mq][nd][1] * inv);
            ov[2] = (short)tobf(o[mq][nd][2] * inv);
            ov[3] = (short)tobf(o[mq][nd][3] * inv);
            *(bf16x4*)(Oa + ((size_t)(b * Tn + q)) * Fn +
                       h * Dn + nd * 16 + (l4 << 2)) = ov;
        }
    }
}

// ---------------------------------------------------------------------------
extern "C" void kernel_launch(void* const* d_in, const int* in_sizes, int n_in,
                              void* d_out, int out_size, void* d_ws, size_t ws_size,
                              hipStream_t stream) {
    const float* q    = (const float*)d_in[0];
    const float* k    = (const float*)d_in[1];
    const float* v    = (const float*)d_in[2];
    const float* cosb = (const float*)d_in[3];
    const float* sinb = (const float*)d_in[4];
    const float* wq   = (const float*)d_in[5];
    const float* wk   = (const float*)d_in[6];
    const float* wv   = (const float*)d_in[7];
    const float* wo   = (const float*)d_in[8];
    const float* bq   = (const float*)d_in[9];
    const float* bk   = (const float*)d_in[10];
    const float* bv   = (const float*)d_in[11];
    const float* bo   = (const float*)d_in[12];

    char* ws = (char*)d_ws;
    const size_t MB = (size_t)1 << 20;
    // Lifetime plan (ws 56 MB):
    //  prep/gemm phase: Aq[0..8) Ak[8..16) Av[16..24) W[24..32) -> Qp/Kr/Vr[32..56)
    //  attn phase: writes final Oa = ws[0..8) (Aq dead after gemm_qkv);
    //              Qp/Kr/Vr live; Wo ws[30..32)
    //  gemm_f32: A=Oa, W=Wo -> C=d_out
    u16* Aq  = (u16*)(ws);
    u16* Ak  = (u16*)(ws + 8 * MB);
    u16* Av  = (u16*)(ws + 16 * MB);
    u16* Wq  = (u16*)(ws + 24 * MB);
    u16* Wk  = (u16*)(ws + 26 * MB);
    u16* Wv  = (u16*)(ws + 28 * MB);
    u16* Wo  = (u16*)(ws + 30 * MB);
    u16* Qp  = (u16*)(ws + 32 * MB);
    u16* Kr  = (u16*)(ws + 40 * MB);
    u16* Vr  = (u16*)(ws + 48 * MB);
    u16* Oa  = Aq;

    k_prep<<<8192, 256, 0, stream>>>(q, k, v, cosb, sinb, wq, wk, wv, wo,
                                     Aq, Ak, Av);
    k_gemm_qkv<<<dim3(8, 32, 3), 256, 0, stream>>>(Aq, Wq, bq, Qp,
                                                   Ak, Wk, bk, Kr,
                                                   Av, Wv, bv, Vr);
    k_attn<<<dim3(32, 16), 256, 0, stream>>>(Qp, Kr, Vr, Oa);
    k_gemm_f32<<<dim3(8, 32), 256, 0, stream>>>(Oa, Wo, bo, (float*)d_out);
}